// Round 6
// baseline (915.918 us; speedup 1.0000x reference)
//
#include <hip/hip_runtime.h>
#include <math.h>

#define N_PTS 1024
#define HID   256
#define FEAT  2048
#define GRID  1024

typedef short bf16x8 __attribute__((ext_vector_type(8)));
typedef float f32x4  __attribute__((ext_vector_type(4)));

__device__ inline ushort f2bf(float f) {
    union { float f; unsigned u; } v; v.f = f;
    unsigned r = v.u + 0x7fff + ((v.u >> 16) & 1);   // round-to-nearest-even
    return (ushort)(r >> 16);
}

// Distributed grid barrier: 64 counter lines (64B apart). Arrival = 1 RMW on
// line (bid&63) -> <=16 serialized RMWs/line in parallel across lines.
// Wave 0 polls: lane L loads line L, shfl-sum, compare vs cumulative target.
// All GRID blocks co-resident: __launch_bounds__(256,4) -> 4 blocks/CU x 256
// CU = 1024. Counters zeroed by a 4KB memset node each launch. Bounded spin:
// deadlock -> wrong answer, never a hang.
__device__ __forceinline__ void gridbar(unsigned* cnt, unsigned target) {
    __syncthreads();
    __threadfence();
    const int tid = threadIdx.x;
    if (tid == 0)
        __hip_atomic_fetch_add(&cnt[(blockIdx.x & 63) * 16], 1u,
                               __ATOMIC_RELEASE, __HIP_MEMORY_SCOPE_AGENT);
    if (tid < 64) {
        unsigned spins = 0;
        for (;;) {
            unsigned v = __hip_atomic_load(&cnt[tid * 16], __ATOMIC_RELAXED,
                                           __HIP_MEMORY_SCOPE_AGENT);
            #pragma unroll
            for (int off = 1; off < 64; off <<= 1) v += __shfl_xor(v, off, 64);
            if (v >= target) break;
            __builtin_amdgcn_s_sleep(32);
            if (++spins > (1u << 16)) break;   // failsafe
        }
    }
    __threadfence();
    __syncthreads();
}

// One megakernel, 6 phases, 5 grid barriers. Phase bodies = verified R4
// kernels; plumbing adapted to 1024 blocks.
__global__ __launch_bounds__(256, 4) void fused_all(
    const float* __restrict__ features, const int* __restrict__ labels,
    const float* __restrict__ W1, const float* __restrict__ g1,
    const float* __restrict__ bt1, const float* __restrict__ W2,
    const float* __restrict__ g2, const float* __restrict__ bt2,
    const float* __restrict__ We1, const float* __restrict__ bwe1,
    const float* __restrict__ We2, const float* __restrict__ bwe2,
    float* __restrict__ out, float* __restrict__ ws)
{
    __shared__ __align__(16) unsigned char smem[24704];

    float* x1    = ws;                 // 262144
    float* hi    = ws + 262144;        // 262144
    float* hj    = ws + 524288;        // 262144
    float* stats = ws + 786432;        // 1024: sum1, sq1, sum2, sq2
    float* x2    = ws + 787456;        // 262144
    float* di    = ws + 1049600;       // 262144
    float* x1p   = ws + 1311744;       // 16 x 262144 split-K partials
    ushort* Af   = (ushort*)(ws + 5506048);   // 1024*2048 bf16
    ushort* W1T  = Af + 2097152;              // 256*2048 bf16
    ushort* W2T  = W1T + 524288;              // 256*256 bf16
    ushort* WeT  = W2T + 65536;               // 256*512 bf16
    unsigned* bar = (unsigned*)(ws + 6920192);   // 64 lines x 64B, memset 0

    const int tid  = threadIdx.x;
    const int bid  = blockIdx.x;
    const int lane = tid & 63;
    const int wave = tid >> 6;
    const int wy = wave >> 1, wx = wave & 1;
    const int quad = lane >> 4, l16 = lane & 15;

    //================ P0: zero stats + bf16 convert + weight transposes =====
    {
        if (bid == 300)
            ((float4*)stats)[tid] = make_float4(0.f, 0.f, 0.f, 0.f);
        // features fp32 -> bf16 (1024 blocks x 256 threads x 8 elems)
        {
            const size_t g = (size_t)bid * 256 + tid;
            float4 v0 = ((const float4*)features)[g * 2];
            float4 v1 = ((const float4*)features)[g * 2 + 1];
            bf16x8 o;
            o[0] = (short)f2bf(v0.x); o[1] = (short)f2bf(v0.y);
            o[2] = (short)f2bf(v0.z); o[3] = (short)f2bf(v0.w);
            o[4] = (short)f2bf(v1.x); o[5] = (short)f2bf(v1.y);
            o[6] = (short)f2bf(v1.z); o[7] = (short)f2bf(v1.w);
            ((bf16x8*)Af)[g] = o;
        }
        // weight 64x64 transpose tiles: fp32 [K][256] -> bf16 [256][K]
        if (bid < 176) {
            ushort* Ts = (ushort*)smem;
            int b = bid; const float* src; ushort* dst; int K;
            if (b < 128)      { src = W1;  dst = W1T; K = 2048; }
            else if (b < 144) { b -= 128; src = W2;  dst = W2T; K = 256; }
            else              { b -= 144; src = We1; dst = WeT; K = 512; }
            const int k0 = (b >> 2) * 64;
            const int n0 = (b & 3) * 64;
            #pragma unroll
            for (int p = 0; p < 4; p++) {
                const int c  = p * 256 + tid;
                const int r  = c >> 4;
                const int cq = c & 15;
                float4 v = *(const float4*)&src[(size_t)(k0 + r) * 256 + n0 + cq * 4];
                Ts[(cq * 4 + 0) * 72 + r] = f2bf(v.x);
                Ts[(cq * 4 + 1) * 72 + r] = f2bf(v.y);
                Ts[(cq * 4 + 2) * 72 + r] = f2bf(v.z);
                Ts[(cq * 4 + 3) * 72 + r] = f2bf(v.w);
            }
            __syncthreads();
            #pragma unroll
            for (int p = 0; p < 2; p++) {
                const int c    = p * 256 + tid;
                const int row  = c >> 3;
                const int col8 = c & 7;
                *(bf16x8*)&dst[(size_t)(n0 + row) * K + k0 + col8 * 8] =
                    *(bf16x8*)&Ts[row * 72 + col8 * 8];
            }
        }
    }
    gridbar(bar, 1 * GRID);

    //================ P1: gemm1 split-K=16, plain-store partials ============
    {
        ushort* As = (ushort*)smem;
        ushort* Bs = (ushort*)(smem + 9216);
        const int x = bid & 3, y = (bid >> 2) & 15, z = bid >> 6;  // z<16
        const int mBase = y * 64, nBase = x * 64, kBeg = z * 128;
        float* C = x1p + (size_t)z * (N_PTS * HID);
        f32x4 acc[2][2] = {};
        for (int ks = kBeg; ks < kBeg + 128; ks += 64) {
            #pragma unroll
            for (int p = 0; p < 2; p++) {
                const int c    = p * 256 + tid;
                const int row  = c >> 3;
                const int col8 = c & 7;
                *(bf16x8*)&As[row * 72 + col8 * 8] =
                    *(const bf16x8*)&Af[(size_t)(mBase + row) * FEAT + ks + col8 * 8];
                *(bf16x8*)&Bs[row * 72 + col8 * 8] =
                    *(const bf16x8*)&W1T[(size_t)(nBase + row) * FEAT + ks + col8 * 8];
            }
            __syncthreads();
            #pragma unroll
            for (int kt = 0; kt < 64; kt += 32) {
                bf16x8 af[2], bfr[2];
                #pragma unroll
                for (int mi = 0; mi < 2; mi++)
                    af[mi] = *(bf16x8*)&As[(wy * 32 + mi * 16 + l16) * 72 + kt + quad * 8];
                #pragma unroll
                for (int ni = 0; ni < 2; ni++)
                    bfr[ni] = *(bf16x8*)&Bs[(wx * 32 + ni * 16 + l16) * 72 + kt + quad * 8];
                #pragma unroll
                for (int mi = 0; mi < 2; mi++)
                    #pragma unroll
                    for (int ni = 0; ni < 2; ni++)
                        acc[mi][ni] = __builtin_amdgcn_mfma_f32_16x16x32_bf16(
                            af[mi], bfr[ni], acc[mi][ni], 0, 0, 0);
            }
            __syncthreads();
        }
        #pragma unroll
        for (int mi = 0; mi < 2; mi++)
            #pragma unroll
            for (int ni = 0; ni < 2; ni++)
                #pragma unroll
                for (int e = 0; e < 4; e++) {
                    const int gm = mBase + wy * 32 + mi * 16 + quad * 4 + e;
                    const int gn = nBase + wx * 32 + ni * 16 + l16;
                    C[(size_t)gm * HID + gn] = acc[mi][ni][e];
                }
    }
    gridbar(bar, 2 * GRID);

    //================ P2: reduce 16 partials -> x1 + colstats1 ==============
    if (bid < 256) {
        const int c = tid;
        const int r0 = bid * 4;
        float s = 0.f, q = 0.f;
        for (int r = r0; r < r0 + 4; ++r) {
            float v = 0.f;
            #pragma unroll
            for (int z = 0; z < 16; z++)
                v += x1p[(size_t)z * (N_PTS * HID) + r * HID + c];
            x1[r * HID + c] = v;
            s += v;
            q = fmaf(v, v, q);
        }
        unsafeAtomicAdd(&stats[c], s);
        unsafeAtomicAdd(&stats[256 + c], q);
    }
    gridbar(bar, 3 * GRID);

    //================ P3: gemm2 + BN1 staged + colstats2 epilogue ===========
    if (bid < 64) {
        ushort* As = (ushort*)smem;
        ushort* Bs = (ushort*)(smem + 9216);
        float* sscale = (float*)(smem + 18432);
        float* sshift = (float*)(smem + 19456);
        float* csum   = (float*)(smem + 20480);
        float* csq    = (float*)(smem + 20736);
        const int x = bid & 3, y = bid >> 2;
        const int mBase = y * 64, nBase = x * 64;
        {
            float m   = stats[tid] * (1.f / 1024.f);
            float var = fmaf(-m, m, stats[256 + tid] * (1.f / 1024.f));
            float rstd = rsqrtf(var + 1e-5f);
            float sc = g1[tid] * rstd;
            sscale[tid] = sc;
            sshift[tid] = fmaf(-m, sc, bt1[tid]);
        }
        if (tid < 64) { csum[tid] = 0.f; csq[tid] = 0.f; }
        __syncthreads();

        f32x4 acc[2][2] = {};
        for (int ks = 0; ks < HID; ks += 64) {
            #pragma unroll
            for (int p = 0; p < 4; p++) {
                const int c  = p * 256 + tid;
                const int r  = c >> 4;
                const int cq = c & 15;
                const int k0 = ks + cq * 4;
                float4 av = *(const float4*)&x1[(size_t)(mBase + r) * HID + k0];
                float v0 = fmaxf(fmaf(sscale[k0 + 0], av.x, sshift[k0 + 0]), 0.f);
                float v1 = fmaxf(fmaf(sscale[k0 + 1], av.y, sshift[k0 + 1]), 0.f);
                float v2 = fmaxf(fmaf(sscale[k0 + 2], av.z, sshift[k0 + 2]), 0.f);
                float v3 = fmaxf(fmaf(sscale[k0 + 3], av.w, sshift[k0 + 3]), 0.f);
                ushort4 ao;
                ao.x = f2bf(v0); ao.y = f2bf(v1); ao.z = f2bf(v2); ao.w = f2bf(v3);
                *(ushort4*)&As[r * 72 + cq * 4] = ao;
            }
            #pragma unroll
            for (int p = 0; p < 2; p++) {
                const int c    = p * 256 + tid;
                const int row  = c >> 3;
                const int col8 = c & 7;
                *(bf16x8*)&Bs[row * 72 + col8 * 8] =
                    *(const bf16x8*)&W2T[(size_t)(nBase + row) * HID + ks + col8 * 8];
            }
            __syncthreads();
            #pragma unroll
            for (int kt = 0; kt < 64; kt += 32) {
                bf16x8 af[2], bfr[2];
                #pragma unroll
                for (int mi = 0; mi < 2; mi++)
                    af[mi] = *(bf16x8*)&As[(wy * 32 + mi * 16 + l16) * 72 + kt + quad * 8];
                #pragma unroll
                for (int ni = 0; ni < 2; ni++)
                    bfr[ni] = *(bf16x8*)&Bs[(wx * 32 + ni * 16 + l16) * 72 + kt + quad * 8];
                #pragma unroll
                for (int mi = 0; mi < 2; mi++)
                    #pragma unroll
                    for (int ni = 0; ni < 2; ni++)
                        acc[mi][ni] = __builtin_amdgcn_mfma_f32_16x16x32_bf16(
                            af[mi], bfr[ni], acc[mi][ni], 0, 0, 0);
            }
            __syncthreads();
        }
        float s[2] = {0.f, 0.f}, q[2] = {0.f, 0.f};
        #pragma unroll
        for (int mi = 0; mi < 2; mi++)
            #pragma unroll
            for (int ni = 0; ni < 2; ni++)
                #pragma unroll
                for (int e = 0; e < 4; e++) {
                    const int gm = mBase + wy * 32 + mi * 16 + quad * 4 + e;
                    const int gn = nBase + wx * 32 + ni * 16 + l16;
                    float v = acc[mi][ni][e];
                    x2[(size_t)gm * HID + gn] = v;
                    s[ni] += v;
                    q[ni] = fmaf(v, v, q[ni]);
                }
        #pragma unroll
        for (int ni = 0; ni < 2; ni++) {
            float sv = s[ni], qv = q[ni];
            sv += __shfl_xor(sv, 16, 64); sv += __shfl_xor(sv, 32, 64);
            qv += __shfl_xor(qv, 16, 64); qv += __shfl_xor(qv, 32, 64);
            if (quad == 0) {
                atomicAdd(&csum[wx * 32 + ni * 16 + l16], sv);
                atomicAdd(&csq [wx * 32 + ni * 16 + l16], qv);
            }
        }
        __syncthreads();
        if (tid < 64) {
            unsafeAtomicAdd(&stats[512 + nBase + tid], csum[tid]);
            unsafeAtomicAdd(&stats[768 + nBase + tid], csq[tid]);
        }
    }
    gridbar(bar, 4 * GRID);

    //================ P4: dual edge GEMM + BN2 staged, plain stores =========
    if (bid < 128) {
        ushort* As = (ushort*)smem;
        ushort* Bs = (ushort*)(smem + 9216);
        float* sscale = (float*)(smem + 18432);
        float* sshift = (float*)(smem + 19456);
        const int x = bid & 3, y = (bid >> 2) & 15, half = bid >> 6;
        const int mBase = y * 64, nBase = x * 64;
        float* C = half ? hj : hi;
        const bool writeDi = (x == 0) && (half == 0);
        {
            float m   = stats[512 + tid] * (1.f / 1024.f);
            float var = fmaf(-m, m, stats[768 + tid] * (1.f / 1024.f));
            float rstd = rsqrtf(var + 1e-5f);
            float sc = g2[tid] * rstd;
            sscale[tid] = sc;
            sshift[tid] = fmaf(-m, sc, bt2[tid]);
        }
        __syncthreads();

        f32x4 acc[2][2] = {};
        for (int ks = 0; ks < HID; ks += 64) {
            #pragma unroll
            for (int p = 0; p < 4; p++) {
                const int c  = p * 256 + tid;
                const int r  = c >> 4;
                const int cq = c & 15;
                const int k0 = ks + cq * 4;
                float4 av = *(const float4*)&x2[(size_t)(mBase + r) * HID + k0];
                float v0 = fmaxf(fmaf(sscale[k0 + 0], av.x, sshift[k0 + 0]), 0.f);
                float v1 = fmaxf(fmaf(sscale[k0 + 1], av.y, sshift[k0 + 1]), 0.f);
                float v2 = fmaxf(fmaf(sscale[k0 + 2], av.z, sshift[k0 + 2]), 0.f);
                float v3 = fmaxf(fmaf(sscale[k0 + 3], av.w, sshift[k0 + 3]), 0.f);
                if (writeDi)
                    *(float4*)&di[(size_t)(mBase + r) * HID + k0] =
                        make_float4(v0, v1, v2, v3);
                ushort4 ao;
                ao.x = f2bf(v0); ao.y = f2bf(v1); ao.z = f2bf(v2); ao.w = f2bf(v3);
                *(ushort4*)&As[r * 72 + cq * 4] = ao;
            }
            #pragma unroll
            for (int p = 0; p < 2; p++) {
                const int c    = p * 256 + tid;
                const int row  = c >> 3;
                const int col8 = c & 7;
                *(bf16x8*)&Bs[row * 72 + col8 * 8] =
                    *(const bf16x8*)&WeT[(size_t)(nBase + row) * 512 + half * 256 + ks + col8 * 8];
            }
            __syncthreads();
            #pragma unroll
            for (int kt = 0; kt < 64; kt += 32) {
                bf16x8 af[2], bfr[2];
                #pragma unroll
                for (int mi = 0; mi < 2; mi++)
                    af[mi] = *(bf16x8*)&As[(wy * 32 + mi * 16 + l16) * 72 + kt + quad * 8];
                #pragma unroll
                for (int ni = 0; ni < 2; ni++)
                    bfr[ni] = *(bf16x8*)&Bs[(wx * 32 + ni * 16 + l16) * 72 + kt + quad * 8];
                #pragma unroll
                for (int mi = 0; mi < 2; mi++)
                    #pragma unroll
                    for (int ni = 0; ni < 2; ni++)
                        acc[mi][ni] = __builtin_amdgcn_mfma_f32_16x16x32_bf16(
                            af[mi], bfr[ni], acc[mi][ni], 0, 0, 0);
            }
            __syncthreads();
        }
        #pragma unroll
        for (int mi = 0; mi < 2; mi++)
            #pragma unroll
            for (int ni = 0; ni < 2; ni++)
                #pragma unroll
                for (int e = 0; e < 4; e++) {
                    const int gm = mBase + wy * 32 + mi * 16 + quad * 4 + e;
                    const int gn = nBase + wx * 32 + ni * 16 + l16;
                    C[(size_t)gm * HID + gn] = acc[mi][ni][e];
                }
    }
    gridbar(bar, 5 * GRID);

    //================ P5: all-pairs edge weights + node update (i = bid) ====
    {
        int*   slab  = (int*)smem;
        int*   list  = (int*)(smem + 4096);
        float (*sacc)[HID] = (float(*)[HID])(smem + 8192);
        float* swsum = (float*)(smem + 24576);
        int*   cnt   = (int*)(smem + 24640);
        const int pid = tid >> 4;
        const int lq  = tid & 15;
        const int i   = bid;

        if (tid == 0) *cnt = 0;
        for (int t = tid; t < N_PTS; t += 256) slab[t] = labels[t];
        __syncthreads();
        const int myLab = slab[i];
        for (int t = tid; t < N_PTS; t += 256)
            if (slab[t] == myLab && t != i) list[atomicAdd(cnt, 1)] = t;
        __syncthreads();
        const int n = *cnt;

        const float4* bw4 = (const float4*)bwe1 + lq * 4;
        const float4* w24 = (const float4*)We2  + lq * 4;
        const float4* hip4 = (const float4*)(hi + (size_t)i * HID) + lq * 4;
        float4 hb[4], w2v[4];
        #pragma unroll
        for (int s = 0; s < 4; s++) {
            float4 a = hip4[s], b = bw4[s];
            hb[s] = make_float4(a.x + b.x, a.y + b.y, a.z + b.z, a.w + b.w);
            w2v[s] = w24[s];
        }
        const float b2 = bwe2[0];

        float4 acc4[4] = {};
        float wloc = 0.f;
        const int rounds = (n + 15) >> 4;
        for (int r = 0; r < rounds; ++r) {
            const int idx = r * 16 + pid;
            const bool valid = idx < n;
            const int jj = valid ? list[idx] : i;
            const float4* hv4 = (const float4*)(hj + (size_t)jj * HID) + lq * 4;
            float4 hv[4];
            #pragma unroll
            for (int s = 0; s < 4; s++) hv[s] = hv4[s];
            float p = 0.f;
            #pragma unroll
            for (int s = 0; s < 4; s++) {
                p = fmaf(fmaxf(hb[s].x + hv[s].x, 0.f), w2v[s].x, p);
                p = fmaf(fmaxf(hb[s].y + hv[s].y, 0.f), w2v[s].y, p);
                p = fmaf(fmaxf(hb[s].z + hv[s].z, 0.f), w2v[s].z, p);
                p = fmaf(fmaxf(hb[s].w + hv[s].w, 0.f), w2v[s].w, p);
            }
            p += __shfl_xor(p, 1, 64);
            p += __shfl_xor(p, 2, 64);
            p += __shfl_xor(p, 4, 64);
            p += __shfl_xor(p, 8, 64);
            const float w = valid ? 1.f / (1.f + expf(-(p + b2))) : 0.f;
            const float4* dv4 = (const float4*)(di + (size_t)jj * HID) + lq * 4;
            #pragma unroll
            for (int s = 0; s < 4; s++) {
                float4 d = dv4[s];
                acc4[s].x = fmaf(w, d.x, acc4[s].x);
                acc4[s].y = fmaf(w, d.y, acc4[s].y);
                acc4[s].z = fmaf(w, d.z, acc4[s].z);
                acc4[s].w = fmaf(w, d.w, acc4[s].w);
            }
            if (lq == 0) wloc += w;
        }
        #pragma unroll
        for (int s = 0; s < 4; s++)
            ((float4*)&sacc[pid][lq * 16])[s] = acc4[s];
        if (lq == 0) swsum[pid] = wloc;
        __syncthreads();

        float at = 0.f;
        #pragma unroll
        for (int g = 0; g < 16; g++) at += sacc[g][tid];
        float wt = 0.f;
        #pragma unroll
        for (int g = 0; g < 16; g++) wt += swsum[g];
        const float dval = di[(size_t)i * HID + tid];
        out[(size_t)i * HID + tid] = dval + (wt > 0.f ? at / wt : 0.f);
    }
}

extern "C" void kernel_launch(void* const* d_in, const int* in_sizes, int n_in,
                              void* d_out, int out_size, void* d_ws, size_t ws_size,
                              hipStream_t stream)
{
    const float* features = (const float*)d_in[0];
    const int*   labels   = (const int*)d_in[1];
    const float* W1   = (const float*)d_in[2];
    // b1/b2 cancel exactly through train-mode BN (mean subtraction)
    const float* g1   = (const float*)d_in[4];
    const float* bt1  = (const float*)d_in[5];
    const float* W2   = (const float*)d_in[6];
    const float* g2   = (const float*)d_in[8];
    const float* bt2  = (const float*)d_in[9];
    const float* We1  = (const float*)d_in[10];
    const float* bwe1 = (const float*)d_in[11];
    const float* We2  = (const float*)d_in[12];
    const float* bwe2 = (const float*)d_in[13];
    float* out = (float*)d_out;
    float* ws  = (float*)d_ws;

    // zero the 64 distributed barrier counter lines (ws is poisoned per run)
    hipMemsetAsync((char*)d_ws + (size_t)6920192 * 4, 0, 4096, stream);

    fused_all<<<dim3(GRID), dim3(256), 0, stream>>>(
        features, labels, W1, g1, bt1, W2, g2, bt2,
        We1, bwe1, We2, bwe2, out, ws);
}

// Round 7
// 131.742 us; speedup vs baseline: 6.9524x; 6.9524x over previous
//
#include <hip/hip_runtime.h>
#include <math.h>

#define N_PTS 1024
#define HID   256
#define FEAT  2048

typedef short bf16x8 __attribute__((ext_vector_type(8)));
typedef float f32x4  __attribute__((ext_vector_type(4)));

__device__ inline ushort f2bf(float f) {
    union { float f; unsigned u; } v; v.f = f;
    unsigned r = v.u + 0x7fff + ((v.u >> 16) & 1);   // round-to-nearest-even
    return (ushort)(r >> 16);
}

// ---------------- prep: fp32->bf16 convert + weight transposes -------------
// b < 512            : features [1024][2048] -> Af bf16 [1024][2048]
// 512 <= b < 640     : W1 [2048][256] -> W1T bf16 [256][2048]
// 640 <= b < 656     : W2 [256][256]  -> W2T bf16 [256][256]
// 656 <= b < 688     : We1 [512][256] -> WeT bf16 [256][512]
__global__ __launch_bounds__(256) void prep(
    const float* __restrict__ features, const float* __restrict__ W1,
    const float* __restrict__ W2, const float* __restrict__ We1,
    ushort* __restrict__ Af, ushort* __restrict__ W1T,
    ushort* __restrict__ W2T, ushort* __restrict__ WeT)
{
    const int tid = threadIdx.x;
    int b = blockIdx.x;
    if (b < 512) {               // straight convert, [m][k] kept
        #pragma unroll
        for (int q = 0; q < 2; q++) {
            const size_t g = (size_t)b * 256 + tid + (size_t)q * 131072;
            float4 v0 = ((const float4*)features)[g * 2];
            float4 v1 = ((const float4*)features)[g * 2 + 1];
            bf16x8 o;
            o[0] = (short)f2bf(v0.x); o[1] = (short)f2bf(v0.y);
            o[2] = (short)f2bf(v0.z); o[3] = (short)f2bf(v0.w);
            o[4] = (short)f2bf(v1.x); o[5] = (short)f2bf(v1.y);
            o[6] = (short)f2bf(v1.z); o[7] = (short)f2bf(v1.w);
            ((bf16x8*)Af)[g] = o;
        }
        return;
    }
    // 64x64 transpose tiles: src fp32 [K][256] -> dst bf16 [256][K]
    __shared__ ushort Ts[64 * 72];
    const float* src; ushort* dst; int K;
    b -= 512;
    if (b < 128)      { src = W1;  dst = W1T; K = 2048; }
    else if (b < 144) { b -= 128; src = W2;  dst = W2T; K = 256; }
    else              { b -= 144; src = We1; dst = WeT; K = 512; }
    const int k0 = (b >> 2) * 64;
    const int n0 = (b & 3) * 64;
    #pragma unroll
    for (int p = 0; p < 4; p++) {
        const int c  = p * 256 + tid;
        const int r  = c >> 4;           // k-local
        const int cq = c & 15;           // n-chunk
        float4 v = *(const float4*)&src[(size_t)(k0 + r) * 256 + n0 + cq * 4];
        Ts[(cq * 4 + 0) * 72 + r] = f2bf(v.x);
        Ts[(cq * 4 + 1) * 72 + r] = f2bf(v.y);
        Ts[(cq * 4 + 2) * 72 + r] = f2bf(v.z);
        Ts[(cq * 4 + 3) * 72 + r] = f2bf(v.w);
    }
    __syncthreads();
    #pragma unroll
    for (int p = 0; p < 2; p++) {
        const int c    = p * 256 + tid;  // 0..511
        const int row  = c >> 3;         // n-local
        const int col8 = c & 7;          // 8-wide k chunk
        *(bf16x8*)&dst[(size_t)(n0 + row) * K + k0 + col8 * 8] =
            *(bf16x8*)&Ts[row * 72 + col8 * 8];
    }
}

// ---- gemm1 full-K with fused colstats1 partials (NO split-K, NO atomics) --
// grid (4, 64): x = 64-col N-tile, y = 16-row M-tile. 256 thr = 4 waves,
// wave w owns cols [64x+16w, +16). BK=128, 16 iterations over K=2048.
// Epilogue: plain-store x1 + per-block column sum/sq -> statsP[y][512].
__global__ __launch_bounds__(256) void gemm1s(
    const ushort* __restrict__ A /*Af*/, const ushort* __restrict__ B /*W1T*/,
    float* __restrict__ X /*x1*/, float* __restrict__ statsP)
{
    __shared__ ushort As[16 * 136];   // [16 rows][128 k], stride 136
    __shared__ ushort Bs[64 * 136];
    const int tid  = threadIdx.x;
    const int lane = tid & 63;
    const int w    = tid >> 6;
    const int quad = lane >> 4, l16 = lane & 15;
    const int mBase = blockIdx.y * 16;
    const int nBase = blockIdx.x * 64;

    f32x4 acc = {};
    for (int ks = 0; ks < FEAT; ks += 128) {
        {   // A: 16x128 bf16 = 256 chunks, 1 per thread
            const int row  = tid >> 4;
            const int col8 = tid & 15;
            *(bf16x8*)&As[row * 136 + col8 * 8] =
                *(const bf16x8*)&A[(size_t)(mBase + row) * FEAT + ks + col8 * 8];
        }
        #pragma unroll
        for (int p = 0; p < 4; p++) {   // B: 64x128 = 1024 chunks, 4/thread
            const int c    = p * 256 + tid;
            const int row  = c >> 4;
            const int col8 = c & 15;
            *(bf16x8*)&Bs[row * 136 + col8 * 8] =
                *(const bf16x8*)&B[(size_t)(nBase + row) * FEAT + ks + col8 * 8];
        }
        __syncthreads();
        #pragma unroll
        for (int kt = 0; kt < 128; kt += 32) {
            bf16x8 af = *(bf16x8*)&As[l16 * 136 + kt + quad * 8];
            bf16x8 bf = *(bf16x8*)&Bs[(w * 16 + l16) * 136 + kt + quad * 8];
            acc = __builtin_amdgcn_mfma_f32_16x16x32_bf16(af, bf, acc, 0, 0, 0);
        }
        __syncthreads();
    }
    // C/D layout: col = l16, row = quad*4 + e  [verified m89/m91]
    float sv = 0.f, qv = 0.f;
    #pragma unroll
    for (int e = 0; e < 4; e++) {
        const int gm = mBase + quad * 4 + e;
        const int gn = nBase + w * 16 + l16;
        X[(size_t)gm * HID + gn] = acc[e];
        sv += acc[e];
        qv = fmaf(acc[e], acc[e], qv);
    }
    // reduce over quads (rows) -> full 16-row column partials
    sv += __shfl_xor(sv, 16, 64); sv += __shfl_xor(sv, 32, 64);
    qv += __shfl_xor(qv, 16, 64); qv += __shfl_xor(qv, 32, 64);
    if (quad == 0) {
        const int c = nBase + w * 16 + l16;
        statsP[blockIdx.y * 512 + c]       = sv;
        statsP[blockIdx.y * 512 + 256 + c] = qv;
    }
}

// ---- layer2 GEMM, full K: BN1 (from statsP) fused into A-staging,
// ---- colstats2 partials plain-stored to stats2P. B pre-converted bf16.
__global__ __launch_bounds__(256) void gemm2_fused(
    const float* __restrict__ A /*x1*/, const ushort* __restrict__ B /*W2T*/,
    float* __restrict__ C /*x2*/, const float* __restrict__ statsP,
    const float* __restrict__ g1, const float* __restrict__ bt1,
    float* __restrict__ stats2P)
{
    __shared__ ushort As[64 * 72];
    __shared__ ushort Bs[64 * 72];
    __shared__ float sscale[HID];
    __shared__ float sshift[HID];
    __shared__ float csum[64];
    __shared__ float csq[64];
    const int tid  = threadIdx.x;
    const int lane = tid & 63;
    const int wave = tid >> 6;
    const int wy = wave >> 1, wx = wave & 1;
    const int quad = lane >> 4, l16 = lane & 15;
    const int mBase = blockIdx.y * 64;
    const int nBase = blockIdx.x * 64;

    {   // aggregate 64 row-partials -> BN1 scale/shift
        float s1 = 0.f, q1 = 0.f;
        #pragma unroll 8
        for (int y = 0; y < 64; y++) {
            s1 += statsP[y * 512 + tid];
            q1 += statsP[y * 512 + 256 + tid];
        }
        float m   = s1 * (1.f / 1024.f);
        float var = fmaf(-m, m, q1 * (1.f / 1024.f));
        float rstd = rsqrtf(var + 1e-5f);
        float sc = g1[tid] * rstd;
        sscale[tid] = sc;
        sshift[tid] = fmaf(-m, sc, bt1[tid]);
    }
    if (tid < 64) { csum[tid] = 0.f; csq[tid] = 0.f; }
    __syncthreads();

    f32x4 acc[2][2] = {};
    for (int ks = 0; ks < HID; ks += 64) {
        #pragma unroll
        for (int p = 0; p < 4; p++) {
            const int c  = p * 256 + tid;
            const int r  = c >> 4;
            const int cq = c & 15;
            const int k0 = ks + cq * 4;
            float4 av = *(const float4*)&A[(size_t)(mBase + r) * HID + k0];
            float v0 = fmaxf(fmaf(sscale[k0 + 0], av.x, sshift[k0 + 0]), 0.f);
            float v1 = fmaxf(fmaf(sscale[k0 + 1], av.y, sshift[k0 + 1]), 0.f);
            float v2 = fmaxf(fmaf(sscale[k0 + 2], av.z, sshift[k0 + 2]), 0.f);
            float v3 = fmaxf(fmaf(sscale[k0 + 3], av.w, sshift[k0 + 3]), 0.f);
            ushort4 ao;
            ao.x = f2bf(v0); ao.y = f2bf(v1); ao.z = f2bf(v2); ao.w = f2bf(v3);
            *(ushort4*)&As[r * 72 + cq * 4] = ao;
        }
        #pragma unroll
        for (int p = 0; p < 2; p++) {
            const int c    = p * 256 + tid;
            const int row  = c >> 3;
            const int col8 = c & 7;
            *(bf16x8*)&Bs[row * 72 + col8 * 8] =
                *(const bf16x8*)&B[(size_t)(nBase + row) * HID + ks + col8 * 8];
        }
        __syncthreads();
        #pragma unroll
        for (int kt = 0; kt < 64; kt += 32) {
            bf16x8 af[2], bfr[2];
            #pragma unroll
            for (int mi = 0; mi < 2; mi++)
                af[mi] = *(bf16x8*)&As[(wy * 32 + mi * 16 + l16) * 72 + kt + quad * 8];
            #pragma unroll
            for (int ni = 0; ni < 2; ni++)
                bfr[ni] = *(bf16x8*)&Bs[(wx * 32 + ni * 16 + l16) * 72 + kt + quad * 8];
            #pragma unroll
            for (int mi = 0; mi < 2; mi++)
                #pragma unroll
                for (int ni = 0; ni < 2; ni++)
                    acc[mi][ni] = __builtin_amdgcn_mfma_f32_16x16x32_bf16(
                        af[mi], bfr[ni], acc[mi][ni], 0, 0, 0);
        }
        __syncthreads();
    }

    float s[2] = {0.f, 0.f}, q[2] = {0.f, 0.f};
    #pragma unroll
    for (int mi = 0; mi < 2; mi++)
        #pragma unroll
        for (int ni = 0; ni < 2; ni++)
            #pragma unroll
            for (int e = 0; e < 4; e++) {
                const int gm = mBase + wy * 32 + mi * 16 + quad * 4 + e;
                const int gn = nBase + wx * 32 + ni * 16 + l16;
                float v = acc[mi][ni][e];
                C[(size_t)gm * HID + gn] = v;
                s[ni] += v;
                q[ni] = fmaf(v, v, q[ni]);
            }
    #pragma unroll
    for (int ni = 0; ni < 2; ni++) {
        float sv = s[ni], qv = q[ni];
        sv += __shfl_xor(sv, 16, 64); sv += __shfl_xor(sv, 32, 64);
        qv += __shfl_xor(qv, 16, 64); qv += __shfl_xor(qv, 32, 64);
        if (quad == 0) {
            atomicAdd(&csum[wx * 32 + ni * 16 + l16], sv);
            atomicAdd(&csq [wx * 32 + ni * 16 + l16], qv);
        }
    }
    __syncthreads();
    if (tid < 64) {
        stats2P[blockIdx.y * 512 + nBase + tid]       = csum[tid];
        stats2P[blockIdx.y * 512 + 256 + nBase + tid] = csq[tid];
    }
}

// ---- dual edge GEMM, full K, plain stores; BN2 (from stats2P) fused into
// ---- A-staging. blockIdx.z = half. (x==0,half==0) blocks emit fp32 di.
__global__ __launch_bounds__(256) void gemm_dual_bn(
    const float* __restrict__ A /*x2*/, const ushort* __restrict__ WeT,
    float* __restrict__ C1 /*hi*/, float* __restrict__ C2 /*hj*/,
    const float* __restrict__ stats2P,
    const float* __restrict__ g2, const float* __restrict__ bt2,
    float* __restrict__ di)
{
    __shared__ ushort As[64 * 72];
    __shared__ ushort Bs[64 * 72];
    __shared__ float sscale[HID];
    __shared__ float sshift[HID];
    const int tid  = threadIdx.x;
    const int lane = tid & 63;
    const int wave = tid >> 6;
    const int wy = wave >> 1, wx = wave & 1;
    const int quad = lane >> 4, l16 = lane & 15;
    const int mBase = blockIdx.y * 64;
    const int nBase = blockIdx.x * 64;
    const int half  = blockIdx.z;
    float* C = half ? C2 : C1;
    const bool writeDi = (blockIdx.x == 0) && (half == 0);

    {   // aggregate 16 row-partials -> BN2 scale/shift
        float s2 = 0.f, q2 = 0.f;
        #pragma unroll
        for (int y = 0; y < 16; y++) {
            s2 += stats2P[y * 512 + tid];
            q2 += stats2P[y * 512 + 256 + tid];
        }
        float m   = s2 * (1.f / 1024.f);
        float var = fmaf(-m, m, q2 * (1.f / 1024.f));
        float rstd = rsqrtf(var + 1e-5f);
        float sc = g2[tid] * rstd;
        sscale[tid] = sc;
        sshift[tid] = fmaf(-m, sc, bt2[tid]);
    }
    __syncthreads();

    f32x4 acc[2][2] = {};
    for (int ks = 0; ks < HID; ks += 64) {
        #pragma unroll
        for (int p = 0; p < 4; p++) {
            const int c  = p * 256 + tid;
            const int r  = c >> 4;
            const int cq = c & 15;
            const int k0 = ks + cq * 4;
            float4 av = *(const float4*)&A[(size_t)(mBase + r) * HID + k0];
            float v0 = fmaxf(fmaf(sscale[k0 + 0], av.x, sshift[k0 + 0]), 0.f);
            float v1 = fmaxf(fmaf(sscale[k0 + 1], av.y, sshift[k0 + 1]), 0.f);
            float v2 = fmaxf(fmaf(sscale[k0 + 2], av.z, sshift[k0 + 2]), 0.f);
            float v3 = fmaxf(fmaf(sscale[k0 + 3], av.w, sshift[k0 + 3]), 0.f);
            if (writeDi)
                *(float4*)&di[(size_t)(mBase + r) * HID + k0] =
                    make_float4(v0, v1, v2, v3);
            ushort4 ao;
            ao.x = f2bf(v0); ao.y = f2bf(v1); ao.z = f2bf(v2); ao.w = f2bf(v3);
            *(ushort4*)&As[r * 72 + cq * 4] = ao;
        }
        #pragma unroll
        for (int p = 0; p < 2; p++) {
            const int c    = p * 256 + tid;
            const int row  = c >> 3;
            const int col8 = c & 7;
            *(bf16x8*)&Bs[row * 72 + col8 * 8] =
                *(const bf16x8*)&WeT[(size_t)(nBase + row) * 512 + half * 256 + ks + col8 * 8];
        }
        __syncthreads();
        #pragma unroll
        for (int kt = 0; kt < 64; kt += 32) {
            bf16x8 af[2], bfr[2];
            #pragma unroll
            for (int mi = 0; mi < 2; mi++)
                af[mi] = *(bf16x8*)&As[(wy * 32 + mi * 16 + l16) * 72 + kt + quad * 8];
            #pragma unroll
            for (int ni = 0; ni < 2; ni++)
                bfr[ni] = *(bf16x8*)&Bs[(wx * 32 + ni * 16 + l16) * 72 + kt + quad * 8];
            #pragma unroll
            for (int mi = 0; mi < 2; mi++)
                #pragma unroll
                for (int ni = 0; ni < 2; ni++)
                    acc[mi][ni] = __builtin_amdgcn_mfma_f32_16x16x32_bf16(
                        af[mi], bfr[ni], acc[mi][ni], 0, 0, 0);
        }
        __syncthreads();
    }
    #pragma unroll
    for (int mi = 0; mi < 2; mi++)
        #pragma unroll
        for (int ni = 0; ni < 2; ni++)
            #pragma unroll
            for (int e = 0; e < 4; e++) {
                const int gm = mBase + wy * 32 + mi * 16 + quad * 4 + e;
                const int gn = nBase + wx * 32 + ni * 16 + l16;
                C[(size_t)gm * HID + gn] = acc[mi][ni][e];
            }
}

// ---------------- fused all-pairs edge network + node update ---------------
__global__ __launch_bounds__(256) void pair_update2(
    const float* __restrict__ di, const float* __restrict__ hi,
    const float* __restrict__ hj, const float* __restrict__ bwe1,
    const float* __restrict__ We2, const float* __restrict__ bwe2,
    const int* __restrict__ labels, float* __restrict__ out)
{
    __shared__ int   slab[N_PTS];
    __shared__ int   list[N_PTS];
    __shared__ int   cnt;
    __shared__ float sacc[16][HID];
    __shared__ float swsum[16];
    const int i   = blockIdx.x;
    const int tid = threadIdx.x;
    const int pid = tid >> 4;
    const int l16 = tid & 15;

    if (tid == 0) cnt = 0;
    for (int t = tid; t < N_PTS; t += 256) slab[t] = labels[t];
    __syncthreads();
    const int myLab = slab[i];
    for (int t = tid; t < N_PTS; t += 256)
        if (slab[t] == myLab && t != i) list[atomicAdd(&cnt, 1)] = t;
    __syncthreads();
    const int n = cnt;

    const float4* hip4 = (const float4*)(hi + (size_t)i * HID) + l16 * 4;
    const float4* bw4  = (const float4*)bwe1 + l16 * 4;
    const float4* w24  = (const float4*)We2  + l16 * 4;
    float4 hb[4], w2[4];
    #pragma unroll
    for (int s = 0; s < 4; s++) {
        float4 a = hip4[s], b = bw4[s];
        hb[s] = make_float4(a.x + b.x, a.y + b.y, a.z + b.z, a.w + b.w);
        w2[s] = w24[s];
    }
    const float b2 = bwe2[0];

    float4 acc[4] = {};
    float wloc = 0.f;
    const int rounds = (n + 15) >> 4;
    for (int r = 0; r < rounds; ++r) {
        const int idx = r * 16 + pid;
        const bool valid = idx < n;
        const int jj = valid ? list[idx] : i;
        const float4* hv4 = (const float4*)(hj + (size_t)jj * HID) + l16 * 4;
        float4 hv[4];
        #pragma unroll
        for (int s = 0; s < 4; s++) hv[s] = hv4[s];
        float p = 0.f;
        #pragma unroll
        for (int s = 0; s < 4; s++) {
            p = fmaf(fmaxf(hb[s].x + hv[s].x, 0.f), w2[s].x, p);
            p = fmaf(fmaxf(hb[s].y + hv[s].y, 0.f), w2[s].y, p);
            p = fmaf(fmaxf(hb[s].z + hv[s].z, 0.f), w2[s].z, p);
            p = fmaf(fmaxf(hb[s].w + hv[s].w, 0.f), w2[s].w, p);
        }
        p += __shfl_xor(p, 1, 64);
        p += __shfl_xor(p, 2, 64);
        p += __shfl_xor(p, 4, 64);
        p += __shfl_xor(p, 8, 64);
        const float w = valid ? 1.f / (1.f + expf(-(p + b2))) : 0.f;
        const float4* dv4 = (const float4*)(di + (size_t)jj * HID) + l16 * 4;
        #pragma unroll
        for (int s = 0; s < 4; s++) {
            float4 d = dv4[s];
            acc[s].x = fmaf(w, d.x, acc[s].x);
            acc[s].y = fmaf(w, d.y, acc[s].y);
            acc[s].z = fmaf(w, d.z, acc[s].z);
            acc[s].w = fmaf(w, d.w, acc[s].w);
        }
        if (l16 == 0) wloc += w;
    }
    #pragma unroll
    for (int s = 0; s < 4; s++)
        ((float4*)&sacc[pid][l16 * 16])[s] = acc[s];
    if (l16 == 0) swsum[pid] = wloc;
    __syncthreads();

    float at = 0.f;
    #pragma unroll
    for (int g = 0; g < 16; g++) at += sacc[g][tid];
    float wt = 0.f;
    #pragma unroll
    for (int g = 0; g < 16; g++) wt += swsum[g];
    const float dval = di[(size_t)i * HID + tid];
    out[(size_t)i * HID + tid] = dval + (wt > 0.f ? at / wt : 0.f);
}

extern "C" void kernel_launch(void* const* d_in, const int* in_sizes, int n_in,
                              void* d_out, int out_size, void* d_ws, size_t ws_size,
                              hipStream_t stream)
{
    const float* features = (const float*)d_in[0];
    const int*   labels   = (const int*)d_in[1];
    const float* W1   = (const float*)d_in[2];
    // b1/b2 cancel exactly through train-mode BN (mean subtraction)
    const float* g1   = (const float*)d_in[4];
    const float* bt1  = (const float*)d_in[5];
    const float* W2   = (const float*)d_in[6];
    const float* g2   = (const float*)d_in[8];
    const float* bt2  = (const float*)d_in[9];
    const float* We1  = (const float*)d_in[10];
    const float* bwe1 = (const float*)d_in[11];
    const float* We2  = (const float*)d_in[12];
    const float* bwe2 = (const float*)d_in[13];
    float* out = (float*)d_out;

    float* ws      = (float*)d_ws;
    float* x1      = ws;               // 262144 (plain stores)
    float* hi      = ws + 262144;      // 262144 (plain stores)
    float* hj      = ws + 524288;      // 262144 (plain stores)
    float* x2      = ws + 786432;      // 262144 (plain stores)
    float* di      = ws + 1048576;     // 262144 (plain stores)
    float* statsP  = ws + 1310720;     // [64][512] col-stat partials (plain)
    float* stats2P = ws + 1343488;     // [16][512] col-stat partials (plain)
    ushort* Af   = (ushort*)(ws + 1351680);   // 1024*2048 bf16
    ushort* W1T  = Af + 2097152;              // 256*2048 bf16
    ushort* W2T  = W1T + 524288;              // 256*256 bf16
    ushort* WeT  = W2T + 65536;               // 256*512 bf16

    dim3 blk(256);
    // bf16 convert + weight pre-transposes (no zeroing needed anywhere)
    prep<<<688, blk, 0, stream>>>(features, W1, W2, We1, Af, W1T, W2T, WeT);
    // layer 1: full-K GEMM, fused colstats1 partials
    gemm1s<<<dim3(4, 64), blk, 0, stream>>>(Af, W1T, x1, statsP);
    // layer 2: x2 = relu(bn1(x1)) @ W2; BN1 aggregated in preamble,
    // colstats2 partials in epilogue
    gemm2_fused<<<dim3(4, 16), blk, 0, stream>>>(x1, W2T, x2, statsP,
                                                 g1, bt1, stats2P);
    // edge net halves + BN2/ReLU fused into A-staging; emits di
    gemm_dual_bn<<<dim3(4, 16, 2), blk, 0, stream>>>(x2, WeT, hi, hj,
                                                     stats2P, g2, bt2, di);
    // fused all-pairs edge weights + node feature update
    pair_update2<<<N_PTS, blk, 0, stream>>>(di, hi, hj, bwe1, We2, bwe2,
                                            labels, out);
}